// Round 7
// baseline (104.023 us; speedup 1.0000x reference)
//
#include <hip/hip_runtime.h>
#include <math.h>

#define HH 256
#define WW 256
#define BB 2
#define NN 256
#define SPLIT 8
#define GPB (NN / SPLIT)          // gaussians per block slice (32)
#define PXT 4                     // pixels per thread
#define BX (HH * WW / (256 * PXT))  // 64 pixel-blocks per slice
#define ALPHA0 0.025f
#define BETA_ 2.0f
#define EPSF 1e-8f
#define PI_F 3.14159265358979323846f

// ws float layout:
//  [0 .. BB*SPLIT*BX)                  per-block zmax partials (1024 floats)
//  [PIX_OFF .. +BB*SPLIT*HW*4)         per-pixel partial accum float4 (rgb, wsum)
#define ZP_OFF 0
#define PIX_OFF 1024                    // 4096 B, 16B aligned

// ---------------- Kernel 1: fused prep + heavy accumulation ---------------
// Per block: (a) λ-min reduce -> scale/alpha (redundant per block, trivial),
// (b) builds its 32-gaussian table slice in LDS with α folded in
//     (v' = v/sqrt(α), msm' = msm/α), (c) 4 pixels/thread over the slice,
// (d) block zmax -> per-block slot (no atomics, poison-safe).
// table layout per gaussian (16 floats):
//  [0..3]  M00 M11 M22 2*M01      [4..7] 2*M02 2*M12 v0' v1'
//  [8..11] v2' msm' app0 app1     [12..15] app2 0 0 0
__global__ void __launch_bounds__(256) accum_kernel(const float* __restrict__ mu,
                                                    const float* __restrict__ rho,
                                                    const float* __restrict__ lambd,
                                                    const float* __restrict__ app,
                                                    const float* __restrict__ K,
                                                    float4* __restrict__ pacc,
                                                    float* __restrict__ zpart) {
    const int by = blockIdx.y;           // b*SPLIT + slice
    const int b = by >> 3;
    const int h = by & (SPLIT - 1);
    const int t = threadIdx.x;
    __shared__ float4 gd[GPB * 4];       // 32 gaussians * 16 floats = 2 KB
    __shared__ float red[256];
    __shared__ float s_scale;

    // --- per-batch lambda min -> scale ---
    const float* lamB = lambd + b * NN * 3;
    float m = 3.4e38f;
    for (int i = t; i < NN * 3; i += 256) m = fminf(m, lamB[i]);
    red[t] = m;
    __syncthreads();
    for (int s = 128; s > 0; s >>= 1) {
        if (t < s) red[t] = fminf(red[t], red[t + s]);
        __syncthreads();
    }
    if (t == 0) {
        float ls = ceilf(log10f(fmaxf(red[0], 1e-6f)));
        s_scale = powf(10.0f, ls);
    }
    __syncthreads();
    const float scale = s_scale;
    const float alpha = ALPHA0 * scale;
    const float sqa = sqrtf(alpha);
    const float rsa = 1.0f / sqa;        // 1/sqrt(alpha)
    const float inv_a = rsa * rsa;       // 1/alpha
    const float a2 = alpha * alpha;

    // --- build gaussian table slice in LDS (alpha folded) ---
    if (t < GPB) {
        const int gi = b * NN + h * GPB + t;
        const float* rp = rho + (size_t)gi * 9;
        const float* mp = mu + (size_t)gi * 3;
        const float* lp = lambd + (size_t)gi * 3;
        const float* ap = app + (size_t)gi * 3;
        float r00 = rp[0], r01 = rp[1], r02 = rp[2];
        float r10 = rp[3], r11 = rp[4], r12 = rp[5];
        float r20 = rp[6], r21 = rp[7], r22 = rp[8];
        float m0 = mp[0], m1 = mp[1], m2 = mp[2];
        float rm0 = r00 * m0 + r10 * m1 + r20 * m2;
        float rm1 = r01 * m0 + r11 * m1 + r21 * m2;
        float rm2 = r02 * m0 + r12 * m1 + r22 * m2;
        float li0 = scale / fmaxf(lp[0], EPSF);
        float li1 = scale / fmaxf(lp[1], EPSF);
        float li2 = scale / fmaxf(lp[2], EPSF);
        float g0 = li0 * rm0, g1 = li1 * rm1, g2 = li2 * rm2;
        float msm = g0 * rm0 + g1 * rm1 + g2 * rm2;
        float M00 = li0 * r00 * r00 + li1 * r01 * r01 + li2 * r02 * r02;
        float M11 = li0 * r10 * r10 + li1 * r11 * r11 + li2 * r12 * r12;
        float M22 = li0 * r20 * r20 + li1 * r21 * r21 + li2 * r22 * r22;
        float M01 = li0 * r00 * r10 + li1 * r01 * r11 + li2 * r02 * r12;
        float M02 = li0 * r00 * r20 + li1 * r01 * r21 + li2 * r02 * r22;
        float M12 = li0 * r10 * r20 + li1 * r11 * r21 + li2 * r12 * r22;
        float v0 = (r00 * g0 + r01 * g1 + r02 * g2) * rsa;
        float v1 = (r10 * g0 + r11 * g1 + r12 * g2) * rsa;
        float v2 = (r20 * g0 + r21 * g1 + r22 * g2) * rsa;
        gd[t * 4 + 0] = make_float4(M00, M11, M22, 2.0f * M01);
        gd[t * 4 + 1] = make_float4(2.0f * M02, 2.0f * M12, v0, v1);
        gd[t * 4 + 2] = make_float4(v2, msm * inv_a, ap[0], ap[1]);
        gd[t * 4 + 3] = make_float4(ap[2], 0.0f, 0.0f, 0.0f);
    }
    __syncthreads();

    // --- per-pixel ray setup (4 pixels per thread, 256 apart) ---
    const float* Kb = K + b * 9;
    const float fx = Kb[0], cx = Kb[2], fy = Kb[4], cy = Kb[5];
    const int pbase = blockIdx.x * (256 * PXT) + t;

    float r0[PXT], r1[PXT], r2[PXT];
    float q0[PXT], q1[PXT], q2[PXT], q3[PXT], q4[PXT], q5[PXT];
    float wsm[PXT], cc0[PXT], cc1[PXT], cc2[PXT], zm[PXT];
#pragma unroll
    for (int j = 0; j < PXT; ++j) {
        const int pix = pbase + 256 * j;
        float rx = ((float)(pix & (WW - 1)) - cx) / fx;
        float ry = ((float)(pix >> 8) - cy) / fy;
        float inn = __builtin_amdgcn_rsqf(rx * rx + ry * ry + 1.0f);
        r0[j] = rx * inn; r1[j] = ry * inn; r2[j] = inn;
        q0[j] = r0[j] * r0[j]; q1[j] = r1[j] * r1[j]; q2[j] = r2[j] * r2[j];
        q3[j] = r0[j] * r1[j]; q4[j] = r0[j] * r2[j]; q5[j] = r1[j] * r2[j];
        wsm[j] = 0.0f; cc0[j] = 0.0f; cc1[j] = 0.0f; cc2[j] = 0.0f;
        zm[j] = -INFINITY;
    }

#pragma unroll 2
    for (int n = 0; n < GPB; ++n) {
        float4 A = gd[n * 4 + 0];   // M00 M11 M22 2M01
        float4 Bv = gd[n * 4 + 1];  // 2M02 2M12 v0' v1'
        float4 C = gd[n * 4 + 2];   // v2' msm' app0 app1
        float4 D = gd[n * 4 + 3];   // app2 - - -
#pragma unroll
        for (int j = 0; j < PXT; ++j) {
            float rsr = fmaf(A.x, q0[j], fmaf(A.y, q1[j], fmaf(A.z, q2[j],
                        fmaf(A.w, q3[j], fmaf(Bv.x, q4[j], Bv.y * q5[j])))));
            float rsm = fmaf(Bv.z, r0[j], fmaf(Bv.w, r1[j], C.x * r2[j]));
            float q = __builtin_amdgcn_rsqf(fmaxf(rsr, EPSF));  // 1/sqrt(rsr)
            float zp = rsm * (q * q);                           // z' = z/sqrt(a)
            zm[j] = fmaxf(zm[j], zp);
            float arg = fminf(fmaf(rsm, zp, -C.y), 8.0f);       // -d/alpha
            float ee = __expf(arg);
            float z2 = zp * zp, z4 = z2 * z2;
            float den = __builtin_amdgcn_rcpf(fmaf(a2, z4, 1.0f)); // 1/(1+z^4)
            float w = ee * q * den;                             // 'a' in finish
            wsm[j] += w;
            cc0[j] = fmaf(w, C.z, cc0[j]);
            cc1[j] = fmaf(w, C.w, cc1[j]);
            cc2[j] = fmaf(w, D.x, cc2[j]);
        }
    }

    float4* dst = pacc + (size_t)by * (HH * WW);
#pragma unroll
    for (int j = 0; j < PXT; ++j)
        dst[pbase + 256 * j] = make_float4(cc0[j], cc1[j], cc2[j], wsm[j]);

    // --- block zmax -> per-block slot (rescale z' -> z by sqrt(alpha)) ---
    float z = sqa * fmaxf(fmaxf(zm[0], zm[1]), fmaxf(zm[2], zm[3]));
    for (int off = 32; off >= 1; off >>= 1)
        z = fmaxf(z, __shfl_down(z, off, 64));
    __syncthreads();
    if ((t & 63) == 0) red[t >> 6] = z;
    __syncthreads();
    if (t == 0)
        zpart[by * BX + blockIdx.x] =
            fmaxf(fmaxf(red[0], red[1]), fmaxf(red[2], red[3]));
}

// ---------------- Kernel 2: epilogue — zmax reduce + bg + normalize -------
__global__ void __launch_bounds__(256) finish_kernel(const float* __restrict__ lambd,
                                                     const float* __restrict__ bg_app,
                                                     float* __restrict__ out,
                                                     const float* __restrict__ zpart,
                                                     const float4* __restrict__ pacc) {
    const int b = blockIdx.y;
    const int t = threadIdx.x;
    __shared__ float red[256];

    // λ-min -> scale/alpha (redundant recompute, trivial)
    const float* lamB = lambd + b * NN * 3;
    float m = 3.4e38f;
    for (int i = t; i < NN * 3; i += 256) m = fminf(m, lamB[i]);
    red[t] = m;
    __syncthreads();
    for (int s = 128; s > 0; s >>= 1) {
        if (t < s) red[t] = fminf(red[t], red[t + s]);
        __syncthreads();
    }
    const float minlam = red[0];
    __syncthreads();

    // zmax over this batch's 512 block slots
    const float* zp = zpart + b * SPLIT * BX;
    red[t] = fmaxf(zp[t], zp[t + 256]);
    __syncthreads();
    for (int s = 128; s > 0; s >>= 1) {
        if (t < s) red[t] = fmaxf(red[t], red[t + s]);
        __syncthreads();
    }
    const float zmax = red[0];

    const float scale = powf(10.0f, ceilf(log10f(fmaxf(minlam, 1e-6f))));
    const float alpha = ALPHA0 * scale;
    const float a = 0.5f * sqrtf(PI_F * alpha);
    const float zbg = BETA_ * zmax;
    const float zb2 = zbg * zbg;
    const float zb4 = zb2 * zb2;
    const float wbg = a / (1.0f + zb4);       // bg_int = a (erfc clipped to 1)
    const float b0 = bg_app[b * 3 + 0], b1 = bg_app[b * 3 + 1], b2 = bg_app[b * 3 + 2];

    const int hw = HH * WW;
    const int tid = blockIdx.x * 256 + t;
    const int p = tid * 4;                    // 4 consecutive pixels per thread
    const float4* acc = pacc + (size_t)(b * SPLIT) * hw;

    float4 o0, o1, o2;
    float* po0 = &o0.x; float* po1 = &o1.x; float* po2 = &o2.x;
    for (int j = 0; j < 4; ++j) {
        float sx = 0.0f, sy = 0.0f, sz = 0.0f, sw = 0.0f;
#pragma unroll
        for (int s = 0; s < SPLIT; ++s) {
            float4 v = acc[p + j + s * hw];
            sx += v.x; sy += v.y; sz += v.z; sw += v.w;
        }
        float tot = fmaf(a, sw, wbg);
        float inv = 1.0f / fmaxf(tot, EPSF);
        po0[j] = fmaf(a, sx, wbg * b0) * inv;
        po1[j] = fmaf(a, sy, wbg * b1) * inv;
        po2[j] = fmaf(a, sz, wbg * b2) * inv;
    }
    *(float4*)(out + (size_t)(b * 3) * hw + p) = o0;
    *(float4*)(out + (size_t)(b * 3 + 1) * hw + p) = o1;
    *(float4*)(out + (size_t)(b * 3 + 2) * hw + p) = o2;
}

extern "C" void kernel_launch(void* const* d_in, const int* in_sizes, int n_in,
                              void* d_out, int out_size, void* d_ws, size_t ws_size,
                              hipStream_t stream) {
    const float* mu = (const float*)d_in[0];
    const float* rho = (const float*)d_in[1];
    const float* lambd = (const float*)d_in[2];
    const float* app = (const float*)d_in[3];
    const float* bg = (const float*)d_in[4];
    const float* K = (const float*)d_in[5];
    float* ws = (float*)d_ws;
    float* out = (float*)d_out;

    dim3 agrid(BX, BB * SPLIT);
    hipLaunchKernelGGL(accum_kernel, agrid, dim3(256), 0, stream,
                       mu, rho, lambd, app, K,
                       (float4*)(ws + PIX_OFF), ws + ZP_OFF);
    dim3 fgrid(HH * WW / (256 * 4), BB);
    hipLaunchKernelGGL(finish_kernel, fgrid, dim3(256), 0, stream,
                       lambd, bg, out, ws + ZP_OFF, (const float4*)(ws + PIX_OFF));
}

// Round 11
// 101.901 us; speedup vs baseline: 1.0208x; 1.0208x over previous
//
#include <hip/hip_runtime.h>
#include <math.h>

#define HH 256
#define WW 256
#define BB 2
#define NN 256
#define SPLIT 8
#define GPB (NN / SPLIT)            // gaussians per block slice (32)
#define PXT 2                       // pixels per thread
#define PBLK (HH * WW / (256 * PXT))  // 128 pixel-blocks per slice
#define ALPHA0 0.025f
#define BETA_ 2.0f
#define EPSF 1e-8f
#define PI_F 3.14159265358979323846f

// ws float layout:
//  [0 .. BB*SPLIT*PBLK)                per-block zmax partials (2048 floats)
//  [PIX_OFF .. +BB*SPLIT*HW*4)         per-pixel partial accum float4 (rgb, wsum)
#define ZP_OFF 0
#define PIX_OFF 2048                    // 8192 B, 16B aligned

// Smallest power of 10 >= m, m in [1e-6, ~10]; == 10^ceil(log10(m)) without
// libcalls (exact for our data: min(lambda) ~0.011, far from decade edges).
__device__ __forceinline__ float pow10_ceil(float m) {
    float s = 1e-6f;
#pragma unroll
    for (int i = 0; i < 8; ++i) s = (s < m) ? s * 10.0f : s;
    return s;
}

// ---------------- Kernel 1: fused prep + heavy accumulation ---------------
// Per block: (a) per-WAVE λ-min shuffle reduce (no barriers, no libcalls),
// (b) lanes 0..31 build the 32-gaussian table slice in LDS (α folded:
//     v' = v/sqrt(α), msm' = msm/α), (c) 2 pixels/thread over the slice,
// (d) block zmax -> per-block slot (no atomics, poison-safe).
// Table layout per gaussian (16 floats):
//  [0..3]  M00 M11 M22 2*M01      [4..7] 2*M02 2*M12 v0' v1'
//  [8..11] v2' msm' app0 app1     [12..15] app2 0 0 0
__global__ void __launch_bounds__(256, 8) accum_kernel(const float* __restrict__ mu,
                                                       const float* __restrict__ rho,
                                                       const float* __restrict__ lambd,
                                                       const float* __restrict__ app,
                                                       const float* __restrict__ K,
                                                       float4* __restrict__ pacc,
                                                       float* __restrict__ zpart) {
    const int by = blockIdx.y;           // b*SPLIT + slice
    const int b = by >> 3;
    const int h = by & (SPLIT - 1);
    const int t = threadIdx.x;
    __shared__ float4 gd[GPB * 4];       // 32 gaussians * 16 floats = 2 KB
    __shared__ float wred[4];

    // --- per-wave lambda min -> scale (barrier-free, libcall-free) ---
    const float* lamB = lambd + b * NN * 3;
    const int lane = t & 63;
    float m = 3.4e38f;
#pragma unroll
    for (int i = 0; i < 12; ++i) m = fminf(m, lamB[lane + 64 * i]);
    for (int off = 32; off >= 1; off >>= 1)
        m = fminf(m, __shfl_xor(m, off, 64));
    const float scale = pow10_ceil(fmaxf(m, 1e-6f));
    const float alpha = ALPHA0 * scale;
    const float sqa = sqrtf(alpha);
    const float rsa = 1.0f / sqa;        // 1/sqrt(alpha)
    const float inv_a = rsa * rsa;       // 1/alpha
    const float a2 = alpha * alpha;

    // --- build gaussian table slice in LDS (alpha folded) ---
    if (t < GPB) {
        const int gi = b * NN + h * GPB + t;
        const float* rp = rho + (size_t)gi * 9;
        const float* mp = mu + (size_t)gi * 3;
        const float* lp = lambd + (size_t)gi * 3;
        const float* ap = app + (size_t)gi * 3;
        float r00 = rp[0], r01 = rp[1], r02 = rp[2];
        float r10 = rp[3], r11 = rp[4], r12 = rp[5];
        float r20 = rp[6], r21 = rp[7], r22 = rp[8];
        float m0 = mp[0], m1 = mp[1], m2 = mp[2];
        float rm0 = r00 * m0 + r10 * m1 + r20 * m2;
        float rm1 = r01 * m0 + r11 * m1 + r21 * m2;
        float rm2 = r02 * m0 + r12 * m1 + r22 * m2;
        float li0 = scale / fmaxf(lp[0], EPSF);
        float li1 = scale / fmaxf(lp[1], EPSF);
        float li2 = scale / fmaxf(lp[2], EPSF);
        float g0 = li0 * rm0, g1 = li1 * rm1, g2 = li2 * rm2;
        float msm = g0 * rm0 + g1 * rm1 + g2 * rm2;
        float M00 = li0 * r00 * r00 + li1 * r01 * r01 + li2 * r02 * r02;
        float M11 = li0 * r10 * r10 + li1 * r11 * r11 + li2 * r12 * r12;
        float M22 = li0 * r20 * r20 + li1 * r21 * r21 + li2 * r22 * r22;
        float M01 = li0 * r00 * r10 + li1 * r01 * r11 + li2 * r02 * r12;
        float M02 = li0 * r00 * r20 + li1 * r01 * r21 + li2 * r02 * r22;
        float M12 = li0 * r10 * r20 + li1 * r11 * r21 + li2 * r12 * r22;
        float v0 = (r00 * g0 + r01 * g1 + r02 * g2) * rsa;
        float v1 = (r10 * g0 + r11 * g1 + r12 * g2) * rsa;
        float v2 = (r20 * g0 + r21 * g1 + r22 * g2) * rsa;
        gd[t * 4 + 0] = make_float4(M00, M11, M22, 2.0f * M01);
        gd[t * 4 + 1] = make_float4(2.0f * M02, 2.0f * M12, v0, v1);
        gd[t * 4 + 2] = make_float4(v2, msm * inv_a, ap[0], ap[1]);
        gd[t * 4 + 3] = make_float4(ap[2], 0.0f, 0.0f, 0.0f);
    }
    __syncthreads();

    // --- per-pixel ray setup (2 pixels per thread, 256 apart) ---
    const float* Kb = K + b * 9;
    const float fx = Kb[0], cx = Kb[2], fy = Kb[4], cy = Kb[5];
    const int pbase = blockIdx.x * (256 * PXT) + t;

    float r0[PXT], r1[PXT], r2[PXT];
    float q0[PXT], q1[PXT], q2[PXT], q3[PXT], q4[PXT], q5[PXT];
    float wsm[PXT], cc0[PXT], cc1[PXT], cc2[PXT], zm[PXT];
#pragma unroll
    for (int j = 0; j < PXT; ++j) {
        const int pix = pbase + 256 * j;
        float rx = ((float)(pix & (WW - 1)) - cx) / fx;
        float ry = ((float)(pix >> 8) - cy) / fy;
        float inn = __builtin_amdgcn_rsqf(rx * rx + ry * ry + 1.0f);
        r0[j] = rx * inn; r1[j] = ry * inn; r2[j] = inn;
        q0[j] = r0[j] * r0[j]; q1[j] = r1[j] * r1[j]; q2[j] = r2[j] * r2[j];
        q3[j] = r0[j] * r1[j]; q4[j] = r0[j] * r2[j]; q5[j] = r1[j] * r2[j];
        wsm[j] = 0.0f; cc0[j] = 0.0f; cc1[j] = 0.0f; cc2[j] = 0.0f;
        zm[j] = -INFINITY;
    }

#pragma unroll 2
    for (int n = 0; n < GPB; ++n) {
        float4 A = gd[n * 4 + 0];   // M00 M11 M22 2M01
        float4 Bv = gd[n * 4 + 1];  // 2M02 2M12 v0' v1'
        float4 C = gd[n * 4 + 2];   // v2' msm' app0 app1
        float4 D = gd[n * 4 + 3];   // app2 - - -
#pragma unroll
        for (int j = 0; j < PXT; ++j) {
            float rsr = fmaf(A.x, q0[j], fmaf(A.y, q1[j], fmaf(A.z, q2[j],
                        fmaf(A.w, q3[j], fmaf(Bv.x, q4[j], Bv.y * q5[j])))));
            float rsm = fmaf(Bv.z, r0[j], fmaf(Bv.w, r1[j], C.x * r2[j]));
            float q = __builtin_amdgcn_rsqf(fmaxf(rsr, EPSF));  // 1/sqrt(rsr)
            float zp = rsm * (q * q);                           // z' = z/sqrt(a)
            zm[j] = fmaxf(zm[j], zp);
            float arg = fminf(fmaf(rsm, zp, -C.y), 8.0f);       // -d/alpha
            float ee = __expf(arg);
            float z2 = zp * zp, z4 = z2 * z2;
            float den = __builtin_amdgcn_rcpf(fmaf(a2, z4, 1.0f)); // 1/(1+z^4)
            float w = ee * q * den;                             // 'a' in finish
            wsm[j] += w;
            cc0[j] = fmaf(w, C.z, cc0[j]);
            cc1[j] = fmaf(w, C.w, cc1[j]);
            cc2[j] = fmaf(w, D.x, cc2[j]);
        }
    }

    float4* dst = pacc + (size_t)by * (HH * WW);
#pragma unroll
    for (int j = 0; j < PXT; ++j)
        dst[pbase + 256 * j] = make_float4(cc0[j], cc1[j], cc2[j], wsm[j]);

    // --- block zmax -> per-block slot (rescale z' -> z by sqrt(alpha)) ---
    float z = sqa * fmaxf(zm[0], zm[1]);
    for (int off = 32; off >= 1; off >>= 1)
        z = fmaxf(z, __shfl_down(z, off, 64));
    if ((t & 63) == 0) wred[t >> 6] = z;
    __syncthreads();
    if (t == 0)
        zpart[by * PBLK + blockIdx.x] =
            fmaxf(fmaxf(wred[0], wred[1]), fmaxf(wred[2], wred[3]));
}

// ---------------- Kernel 2: epilogue — zmax reduce + bg + normalize -------
__global__ void __launch_bounds__(256) finish_kernel(const float* __restrict__ lambd,
                                                     const float* __restrict__ bg_app,
                                                     float* __restrict__ out,
                                                     const float* __restrict__ zpart,
                                                     const float4* __restrict__ pacc) {
    const int b = blockIdx.y;
    const int t = threadIdx.x;
    __shared__ float red[256];

    // λ-min -> scale/alpha (per-wave shuffle, then same value in all lanes)
    const float* lamB = lambd + b * NN * 3;
    const int lane = t & 63;
    float m = 3.4e38f;
#pragma unroll
    for (int i = 0; i < 12; ++i) m = fminf(m, lamB[lane + 64 * i]);
    for (int off = 32; off >= 1; off >>= 1)
        m = fminf(m, __shfl_xor(m, off, 64));
    const float scale = pow10_ceil(fmaxf(m, 1e-6f));

    // zmax over this batch's SPLIT*PBLK = 1024 block slots
    const float* zp = zpart + b * SPLIT * PBLK;
    float zmv = fmaxf(fmaxf(zp[t], zp[t + 256]), fmaxf(zp[t + 512], zp[t + 768]));
    red[t] = zmv;
    __syncthreads();
    for (int s = 128; s > 0; s >>= 1) {
        if (t < s) red[t] = fmaxf(red[t], red[t + s]);
        __syncthreads();
    }
    const float zmax = red[0];

    const float alpha = ALPHA0 * scale;
    const float a = 0.5f * sqrtf(PI_F * alpha);
    const float zbg = BETA_ * zmax;
    const float zb2 = zbg * zbg;
    const float zb4 = zb2 * zb2;
    const float wbg = a / (1.0f + zb4);       // bg_int = a (erfc clipped to 1)
    const float b0 = bg_app[b * 3 + 0], b1 = bg_app[b * 3 + 1], b2 = bg_app[b * 3 + 2];

    const int hw = HH * WW;
    const int tid = blockIdx.x * 256 + t;
    const int p = tid * 4;                    // 4 consecutive pixels per thread
    const float4* acc = pacc + (size_t)(b * SPLIT) * hw;

    float4 o0, o1, o2;
    float* po0 = &o0.x; float* po1 = &o1.x; float* po2 = &o2.x;
    for (int j = 0; j < 4; ++j) {
        float sx = 0.0f, sy = 0.0f, sz = 0.0f, sw = 0.0f;
#pragma unroll
        for (int s = 0; s < SPLIT; ++s) {
            float4 v = acc[p + j + s * hw];
            sx += v.x; sy += v.y; sz += v.z; sw += v.w;
        }
        float tot = fmaf(a, sw, wbg);
        float inv = 1.0f / fmaxf(tot, EPSF);
        po0[j] = fmaf(a, sx, wbg * b0) * inv;
        po1[j] = fmaf(a, sy, wbg * b1) * inv;
        po2[j] = fmaf(a, sz, wbg * b2) * inv;
    }
    *(float4*)(out + (size_t)(b * 3) * hw + p) = o0;
    *(float4*)(out + (size_t)(b * 3 + 1) * hw + p) = o1;
    *(float4*)(out + (size_t)(b * 3 + 2) * hw + p) = o2;
}

extern "C" void kernel_launch(void* const* d_in, const int* in_sizes, int n_in,
                              void* d_out, int out_size, void* d_ws, size_t ws_size,
                              hipStream_t stream) {
    const float* mu = (const float*)d_in[0];
    const float* rho = (const float*)d_in[1];
    const float* lambd = (const float*)d_in[2];
    const float* app = (const float*)d_in[3];
    const float* bg = (const float*)d_in[4];
    const float* K = (const float*)d_in[5];
    float* ws = (float*)d_ws;
    float* out = (float*)d_out;

    dim3 agrid(PBLK, BB * SPLIT);
    hipLaunchKernelGGL(accum_kernel, agrid, dim3(256), 0, stream,
                       mu, rho, lambd, app, K,
                       (float4*)(ws + PIX_OFF), ws + ZP_OFF);
    dim3 fgrid(HH * WW / (256 * 4), BB);
    hipLaunchKernelGGL(finish_kernel, fgrid, dim3(256), 0, stream,
                       lambd, bg, out, ws + ZP_OFF, (const float4*)(ws + PIX_OFF));
}

// Round 17
// 96.640 us; speedup vs baseline: 1.0764x; 1.0544x over previous
//
#include <hip/hip_runtime.h>
#include <math.h>

#define HH 256
#define WW 256
#define BB 2
#define NN 256
#define SPLIT 8
#define GPB (NN / SPLIT)            // gaussians per block slice (32)
#define PXT 2                       // pixels per thread
#define PBLK (HH * WW / (256 * PXT))  // 128 pixel-blocks per slice
#define ALPHA0 0.025f
#define BETA_ 2.0f
#define EPSF 1e-8f
#define PI_F 3.14159265358979323846f
#define CULL_ARG (-80.0f)           // e^-80*qmax*N << any wbg: exact-safe cull

// ws float layout:
//  [0 .. BB*SPLIT*PBLK)                per-block zmax partials (2048 floats)
//  [PIX_OFF .. +BB*SPLIT*HW*4)         per-pixel partial accum float4 (rgb, wsum)
#define ZP_OFF 0
#define PIX_OFF 2048                    // 8192 B, 16B aligned

// Smallest power of 10 >= m, m in [1e-6, ~10]; == 10^ceil(log10(m)) without
// libcalls (exact for our data: min(lambda) ~0.011, far from decade edges).
__device__ __forceinline__ float pow10_ceil(float m) {
    float s = 1e-6f;
#pragma unroll
    for (int i = 0; i < 8; ++i) s = (s < m) ? s * 10.0f : s;
    return s;
}

// ---------------- Kernel 1: fused prep + heavy accumulation ---------------
// Per block: (a) per-WAVE λ-min shuffle reduce, (b) lanes 0..31 build the
// 32-gaussian table slice in LDS (α folded: v'=v/sqrt(α), msm'=msm/α),
// (c) 2 pixels/thread; per gaussian the mandatory z/zmax part always runs,
// the exp/density/accumulate part runs only if ANY lane's weight is
// representable (wave ballot; skip is numerically exact, see CULL_ARG),
// (d) block zmax -> per-block slot (no atomics, poison-safe).
__global__ void __launch_bounds__(256, 8) accum_kernel(const float* __restrict__ mu,
                                                       const float* __restrict__ rho,
                                                       const float* __restrict__ lambd,
                                                       const float* __restrict__ app,
                                                       const float* __restrict__ K,
                                                       float4* __restrict__ pacc,
                                                       float* __restrict__ zpart) {
    const int by = blockIdx.y;           // b*SPLIT + slice
    const int b = by >> 3;
    const int h = by & (SPLIT - 1);
    const int t = threadIdx.x;
    __shared__ float4 gd[GPB * 4];       // 32 gaussians * 16 floats = 2 KB
    __shared__ float wred[4];

    // --- per-wave lambda min -> scale (barrier-free, libcall-free) ---
    const float* lamB = lambd + b * NN * 3;
    const int lane = t & 63;
    float m = 3.4e38f;
#pragma unroll
    for (int i = 0; i < 12; ++i) m = fminf(m, lamB[lane + 64 * i]);
    for (int off = 32; off >= 1; off >>= 1)
        m = fminf(m, __shfl_xor(m, off, 64));
    const float scale = pow10_ceil(fmaxf(m, 1e-6f));
    const float alpha = ALPHA0 * scale;
    const float sqa = sqrtf(alpha);
    const float rsa = 1.0f / sqa;        // 1/sqrt(alpha)
    const float inv_a = rsa * rsa;       // 1/alpha
    const float a2 = alpha * alpha;

    // --- build gaussian table slice in LDS (alpha folded) ---
    if (t < GPB) {
        const int gi = b * NN + h * GPB + t;
        const float* rp = rho + (size_t)gi * 9;
        const float* mp = mu + (size_t)gi * 3;
        const float* lp = lambd + (size_t)gi * 3;
        const float* ap = app + (size_t)gi * 3;
        float r00 = rp[0], r01 = rp[1], r02 = rp[2];
        float r10 = rp[3], r11 = rp[4], r12 = rp[5];
        float r20 = rp[6], r21 = rp[7], r22 = rp[8];
        float m0 = mp[0], m1 = mp[1], m2 = mp[2];
        float rm0 = r00 * m0 + r10 * m1 + r20 * m2;
        float rm1 = r01 * m0 + r11 * m1 + r21 * m2;
        float rm2 = r02 * m0 + r12 * m1 + r22 * m2;
        float li0 = scale / fmaxf(lp[0], EPSF);
        float li1 = scale / fmaxf(lp[1], EPSF);
        float li2 = scale / fmaxf(lp[2], EPSF);
        float g0 = li0 * rm0, g1 = li1 * rm1, g2 = li2 * rm2;
        float msm = g0 * rm0 + g1 * rm1 + g2 * rm2;
        float M00 = li0 * r00 * r00 + li1 * r01 * r01 + li2 * r02 * r02;
        float M11 = li0 * r10 * r10 + li1 * r11 * r11 + li2 * r12 * r12;
        float M22 = li0 * r20 * r20 + li1 * r21 * r21 + li2 * r22 * r22;
        float M01 = li0 * r00 * r10 + li1 * r01 * r11 + li2 * r02 * r12;
        float M02 = li0 * r00 * r20 + li1 * r01 * r21 + li2 * r02 * r22;
        float M12 = li0 * r10 * r20 + li1 * r11 * r21 + li2 * r12 * r22;
        float v0 = (r00 * g0 + r01 * g1 + r02 * g2) * rsa;
        float v1 = (r10 * g0 + r11 * g1 + r12 * g2) * rsa;
        float v2 = (r20 * g0 + r21 * g1 + r22 * g2) * rsa;
        gd[t * 4 + 0] = make_float4(M00, M11, M22, 2.0f * M01);
        gd[t * 4 + 1] = make_float4(2.0f * M02, 2.0f * M12, v0, v1);
        gd[t * 4 + 2] = make_float4(v2, msm * inv_a, ap[0], ap[1]);
        gd[t * 4 + 3] = make_float4(ap[2], 0.0f, 0.0f, 0.0f);
    }
    __syncthreads();

    // --- per-pixel ray setup (2 pixels per thread, 256 apart) ---
    const float* Kb = K + b * 9;
    const float fx = Kb[0], cx = Kb[2], fy = Kb[4], cy = Kb[5];
    const int pbase = blockIdx.x * (256 * PXT) + t;

    float r0[PXT], r1[PXT], r2[PXT];
    float q0[PXT], q1[PXT], q2[PXT], q3[PXT], q4[PXT], q5[PXT];
    float wsm[PXT], cc0[PXT], cc1[PXT], cc2[PXT], zm[PXT];
#pragma unroll
    for (int j = 0; j < PXT; ++j) {
        const int pix = pbase + 256 * j;
        float rx = ((float)(pix & (WW - 1)) - cx) / fx;
        float ry = ((float)(pix >> 8) - cy) / fy;
        float inn = __builtin_amdgcn_rsqf(rx * rx + ry * ry + 1.0f);
        r0[j] = rx * inn; r1[j] = ry * inn; r2[j] = inn;
        q0[j] = r0[j] * r0[j]; q1[j] = r1[j] * r1[j]; q2[j] = r2[j] * r2[j];
        q3[j] = r0[j] * r1[j]; q4[j] = r0[j] * r2[j]; q5[j] = r1[j] * r2[j];
        wsm[j] = 0.0f; cc0[j] = 0.0f; cc1[j] = 0.0f; cc2[j] = 0.0f;
        zm[j] = -INFINITY;
    }

    for (int n = 0; n < GPB; ++n) {
        float4 A = gd[n * 4 + 0];   // M00 M11 M22 2M01
        float4 Bv = gd[n * 4 + 1];  // 2M02 2M12 v0' v1'
        float4 C = gd[n * 4 + 2];   // v2' msm' app0 app1

        // mandatory part: z (for global zmax) + cull predicate
        float rsr[PXT], rsm[PXT], qv[PXT], zp[PXT], arg[PXT];
#pragma unroll
        for (int j = 0; j < PXT; ++j) {
            rsr[j] = fmaf(A.x, q0[j], fmaf(A.y, q1[j], fmaf(A.z, q2[j],
                     fmaf(A.w, q3[j], fmaf(Bv.x, q4[j], Bv.y * q5[j])))));
            rsm[j] = fmaf(Bv.z, r0[j], fmaf(Bv.w, r1[j], C.x * r2[j]));
            qv[j] = __builtin_amdgcn_rsqf(fmaxf(rsr[j], EPSF)); // 1/sqrt(rsr)
            zp[j] = rsm[j] * (qv[j] * qv[j]);                   // z' = z/sqrt(a)
            zm[j] = fmaxf(zm[j], zp[j]);
            arg[j] = fmaf(rsm[j], zp[j], -C.y);                 // -d/alpha
        }

        // weight part: only if any lane of the wave has representable mass
        if (__any(fmaxf(arg[0], arg[1]) > CULL_ARG)) {
            float4 D = gd[n * 4 + 3];   // app2 - - -
#pragma unroll
            for (int j = 0; j < PXT; ++j) {
                float ee = __expf(fminf(arg[j], 8.0f));
                float z2 = zp[j] * zp[j], z4 = z2 * z2;
                float den = __builtin_amdgcn_rcpf(fmaf(a2, z4, 1.0f));
                float w = ee * qv[j] * den;                     // 'a' in finish
                wsm[j] += w;
                cc0[j] = fmaf(w, C.z, cc0[j]);
                cc1[j] = fmaf(w, C.w, cc1[j]);
                cc2[j] = fmaf(w, D.x, cc2[j]);
            }
        }
    }

    float4* dst = pacc + (size_t)by * (HH * WW);
#pragma unroll
    for (int j = 0; j < PXT; ++j)
        dst[pbase + 256 * j] = make_float4(cc0[j], cc1[j], cc2[j], wsm[j]);

    // --- block zmax -> per-block slot (rescale z' -> z by sqrt(alpha)) ---
    float z = sqa * fmaxf(zm[0], zm[1]);
    for (int off = 32; off >= 1; off >>= 1)
        z = fmaxf(z, __shfl_down(z, off, 64));
    if ((t & 63) == 0) wred[t >> 6] = z;
    __syncthreads();
    if (t == 0)
        zpart[by * PBLK + blockIdx.x] =
            fmaxf(fmaxf(wred[0], wred[1]), fmaxf(wred[2], wred[3]));
}

// ---------------- Kernel 2: epilogue — zmax reduce + bg + normalize -------
__global__ void __launch_bounds__(256) finish_kernel(const float* __restrict__ lambd,
                                                     const float* __restrict__ bg_app,
                                                     float* __restrict__ out,
                                                     const float* __restrict__ zpart,
                                                     const float4* __restrict__ pacc) {
    const int b = blockIdx.y;
    const int t = threadIdx.x;
    __shared__ float red[256];

    // λ-min -> scale/alpha (per-wave shuffle, then same value in all lanes)
    const float* lamB = lambd + b * NN * 3;
    const int lane = t & 63;
    float m = 3.4e38f;
#pragma unroll
    for (int i = 0; i < 12; ++i) m = fminf(m, lamB[lane + 64 * i]);
    for (int off = 32; off >= 1; off >>= 1)
        m = fminf(m, __shfl_xor(m, off, 64));
    const float scale = pow10_ceil(fmaxf(m, 1e-6f));

    // zmax over this batch's SPLIT*PBLK = 1024 block slots
    const float* zp = zpart + b * SPLIT * PBLK;
    float zmv = fmaxf(fmaxf(zp[t], zp[t + 256]), fmaxf(zp[t + 512], zp[t + 768]));
    red[t] = zmv;
    __syncthreads();
    for (int s = 128; s > 0; s >>= 1) {
        if (t < s) red[t] = fmaxf(red[t], red[t + s]);
        __syncthreads();
    }
    const float zmax = red[0];

    const float alpha = ALPHA0 * scale;
    const float a = 0.5f * sqrtf(PI_F * alpha);
    const float zbg = BETA_ * zmax;
    const float zb2 = zbg * zbg;
    const float zb4 = zb2 * zb2;
    const float wbg = a / (1.0f + zb4);       // bg_int = a (erfc clipped to 1)
    const float b0 = bg_app[b * 3 + 0], b1 = bg_app[b * 3 + 1], b2 = bg_app[b * 3 + 2];

    const int hw = HH * WW;
    const int tid = blockIdx.x * 256 + t;
    const int p = tid * 4;                    // 4 consecutive pixels per thread
    const float4* acc = pacc + (size_t)(b * SPLIT) * hw;

    float4 o0, o1, o2;
    float* po0 = &o0.x; float* po1 = &o1.x; float* po2 = &o2.x;
    for (int j = 0; j < 4; ++j) {
        float sx = 0.0f, sy = 0.0f, sz = 0.0f, sw = 0.0f;
#pragma unroll
        for (int s = 0; s < SPLIT; ++s) {
            float4 v = acc[p + j + s * hw];
            sx += v.x; sy += v.y; sz += v.z; sw += v.w;
        }
        float tot = fmaf(a, sw, wbg);
        float inv = 1.0f / fmaxf(tot, EPSF);
        po0[j] = fmaf(a, sx, wbg * b0) * inv;
        po1[j] = fmaf(a, sy, wbg * b1) * inv;
        po2[j] = fmaf(a, sz, wbg * b2) * inv;
    }
    *(float4*)(out + (size_t)(b * 3) * hw + p) = o0;
    *(float4*)(out + (size_t)(b * 3 + 1) * hw + p) = o1;
    *(float4*)(out + (size_t)(b * 3 + 2) * hw + p) = o2;
}

extern "C" void kernel_launch(void* const* d_in, const int* in_sizes, int n_in,
                              void* d_out, int out_size, void* d_ws, size_t ws_size,
                              hipStream_t stream) {
    const float* mu = (const float*)d_in[0];
    const float* rho = (const float*)d_in[1];
    const float* lambd = (const float*)d_in[2];
    const float* app = (const float*)d_in[3];
    const float* bg = (const float*)d_in[4];
    const float* K = (const float*)d_in[5];
    float* ws = (float*)d_ws;
    float* out = (float*)d_out;

    dim3 agrid(PBLK, BB * SPLIT);
    hipLaunchKernelGGL(accum_kernel, agrid, dim3(256), 0, stream,
                       mu, rho, lambd, app, K,
                       (float4*)(ws + PIX_OFF), ws + ZP_OFF);
    dim3 fgrid(HH * WW / (256 * 4), BB);
    hipLaunchKernelGGL(finish_kernel, fgrid, dim3(256), 0, stream,
                       lambd, bg, out, ws + ZP_OFF, (const float4*)(ws + PIX_OFF));
}